// Round 5
// baseline (118.258 us; speedup 1.0000x reference)
//
#include <hip/hip_runtime.h>

// Problem constants (match reference setup_inputs).
#define BB 4
#define CC 128
#define CE 64
#define VV 4096
#define NLEV 14   // MAX_LEVELS

// Workspace layout:
//   wsort [BB*VV] float : edge weight of node at SORTED position i
//   giInv [BB*VV] int   : levelpos of pixel v (inverse of levelorder*sorted_index)
//   pw    [BB*VV] int2  : {cp (levelpos of parent), w bits} at levelpos k
//   inr   [BB*VV] float : 1 / nrm_final at levelpos k
//   offs  [BB*16] int   : level start offsets

__device__ __forceinline__ void lds_fadd(float* p, float v) {
    unsafeAtomicAdd(p, v);   // ds_add_f32 on gfx950 LDS
}

// ---------------------------------------------------------------------------
// K1: edge weights in SORTED order — independent of the sort kernel.
//     Block = 64 nodes; wave w covers ce chunk [16w,16w+16). Each gather has
//     64 lanes within ONE 16 KB embed row -> L1-resident after first touch.
// ---------------------------------------------------------------------------
__global__ __launch_bounds__(256) void weight_kernel(
    const float* __restrict__ embed,
    const int* __restrict__ sorted_index,
    const int* __restrict__ sorted_parent,
    float* __restrict__ wsort)
{
    __shared__ float part[4][64];
    int bb   = blockIdx.x;
    int b    = bb >> 6;            // 64 blocks per batch
    int n0   = (bb & 63) << 6;
    int lane = threadIdx.x & 63;
    int w    = threadIdx.x >> 6;
    int i    = n0 + lane;
    int vi = sorted_index[b * VV + i];
    int p  = sorted_parent[b * VV + i];
    int vp = sorted_index[b * VV + p];
    const float* eb = embed + (size_t)b * CE * VV;
    float acc = 0.f;
    #pragma unroll
    for (int r = 0; r < 16; ++r) {
        int ce = w * 16 + r;
        float d = eb[ce * VV + vi] - eb[ce * VV + vp];
        acc = fmaf(d, d, acc);
    }
    part[w][lane] = acc;
    __syncthreads();
    if (w == 0) {
        float d2 = part[0][lane] + part[1][lane] + part[2][lane] + part[3][lane];
        wsort[b * VV + i] = __expf(-d2);
    }
}

// ---------------------------------------------------------------------------
// K2: per-batch counting sort + FUSED normalizer chain (channel-independent).
//     Only 4 blocks, but the chip is idle here anyway; doing nrm once removes
//     half the LDS atomics from all 512 tree blocks.
// ---------------------------------------------------------------------------
__global__ __launch_bounds__(256) void sortnrm_kernel(
    const int* __restrict__ sorted_index,
    const int* __restrict__ sorted_parent,
    const int* __restrict__ node_level,
    const float* __restrict__ wsort,
    int* __restrict__ giInv,
    int2* __restrict__ pw,
    float* __restrict__ inr,
    int* __restrict__ offs)
{
    __shared__ int   si_s[VV];
    __shared__ int   pos_s[VV];
    __shared__ int   lo_s[VV];
    __shared__ int   cp_s[VV];
    __shared__ float w_s[VV];
    __shared__ float vn[VV];
    __shared__ int hist[NLEV + 1];
    __shared__ int cursor[NLEV];
    __shared__ int offS[NLEV + 1];
    int b = blockIdx.x, tid = threadIdx.x;
    const int* lev = node_level    + b * VV;
    const int* si  = sorted_index  + b * VV;
    const int* par = sorted_parent + b * VV;

    if (tid < NLEV + 1) hist[tid] = 0;
    __syncthreads();
    for (int i = tid; i < VV; i += 256) {
        si_s[i] = si[i];
        int d = lev[i]; d = d < NLEV - 1 ? d : NLEV - 1;
        atomicAdd(&hist[d], 1);
    }
    __syncthreads();
    if (tid == 0) {
        int acc = 0;
        for (int d = 0; d < NLEV; ++d) { int h = hist[d]; offS[d] = acc; cursor[d] = acc; acc += h; }
        offS[NLEV] = acc;
    }
    __syncthreads();
    if (tid <= NLEV) offs[b * 16 + tid] = offS[tid];
    for (int i = tid; i < VV; i += 256) {
        int d = lev[i]; d = d < NLEV - 1 ? d : NLEV - 1;
        int k = atomicAdd(&cursor[d], 1);
        pos_s[i] = k;
        lo_s[k]  = i;
        giInv[b * VV + si_s[i]] = k;
    }
    __syncthreads();
    for (int k = tid; k < VV; k += 256) {
        int i = lo_s[k];
        cp_s[k] = pos_s[par[i]];
        w_s[k]  = wsort[b * VV + i];
        vn[k]   = 1.0f;
    }
    __syncthreads();
    for (int k = tid; k < VV; k += 256)
        pw[b * VV + k] = make_int2(cp_s[k], __float_as_int(w_s[k]));
    // nrm chain: up then down, barriers only on non-empty levels
    for (int d = NLEV - 1; d >= 1; --d) {
        int s = offS[d], e = offS[d + 1];
        if (s == e) continue;
        for (int k = s + tid; k < e; k += 256)
            lds_fadd(&vn[cp_s[k]], w_s[k] * vn[k]);
        __syncthreads();
    }
    for (int d = 1; d <= NLEV - 1; ++d) {
        int s = offS[d], e = offS[d + 1];
        if (s == e) continue;
        for (int k = s + tid; k < e; k += 256) {
            float u = vn[k], wk = w_s[k];
            vn[k] = fmaf(wk, fmaf(-wk, u, vn[cp_s[k]]), u);
        }
        __syncthreads();
    }
    for (int k = tid; k < VV; k += 256)
        inr[b * VV + k] = 1.0f / vn[k];
}

// ---------------------------------------------------------------------------
// K3: per-(b,c) tree filter, val-only chain (nrm precomputed). 4 waves/block,
//     512 blocks, 64 KB LDS -> 2 blocks/CU, 8 waves/CU. All global traffic
//     coalesced float4/int4; scatter/gather confined to LDS b32 ops.
// ---------------------------------------------------------------------------
__global__ __launch_bounds__(256) void tree_kernel(
    const float* __restrict__ feat,
    const int* __restrict__ giInv,
    const int2* __restrict__ pw,
    const float* __restrict__ inr,
    const int* __restrict__ offs,
    float* __restrict__ out)
{
    __shared__ float val[VV];    // 16 KB
    __shared__ int2  pwS[VV];    // 32 KB
    __shared__ float inrS[VV];   // 16 KB
    __shared__ int   offS[16];
    int b   = blockIdx.x >> 7;   // CC = 128
    int c   = blockIdx.x & (CC - 1);
    int tid = threadIdx.x;

    const int2*  pwB = pw    + b * VV;
    const int*   ivB = giInv + b * VV;
    const float* inB = inr   + b * VV;
    const float* f   = feat + ((size_t)(b * CC + c)) * VV;

    if (tid < 16) offS[tid] = offs[b * 16 + tid];

    // stage pw pairs (b128) and invnrm (b128), fully coalesced
    #pragma unroll
    for (int t = 0; t < 8; ++t) {
        int idx = tid + t * 256;
        ((int4*)pwS)[idx] = ((const int4*)pwB)[idx];
    }
    #pragma unroll
    for (int t = 0; t < 4; ++t) {
        int idx = tid + t * 256;
        ((float4*)inrS)[idx] = ((const float4*)inB)[idx];
    }

    // init: coalesced float4/int4 reads, scattered b32 LDS writes
    #pragma unroll
    for (int t = 0; t < 4; ++t) {
        int idx = tid + t * 256;
        float4 fv = ((const float4*)f)[idx];
        int4   kk = ((const int4*)ivB)[idx];
        val[kk.x] = fv.x; val[kk.y] = fv.y; val[kk.z] = fv.z; val[kk.w] = fv.w;
    }
    __syncthreads();

    // upward: parents of level d are exactly level d-1 -> phase-safe atomics
    for (int d = NLEV - 1; d >= 1; --d) {
        int s = offS[d], e = offS[d + 1];
        if (s == e) continue;
        for (int k = s + tid; k < e; k += 256) {
            int2 cw = pwS[k];
            lds_fadd(&val[cw.x], __int_as_float(cw.y) * val[k]);
        }
        __syncthreads();
    }

    // downward: in place; parent (level d-1) final before level d reads it
    for (int d = 1; d <= NLEV - 1; ++d) {
        int s = offS[d], e = offS[d + 1];
        if (s == e) continue;
        for (int k = s + tid; k < e; k += 256) {
            int2 cw = pwS[k];
            float w = __int_as_float(cw.y);
            float u = val[k];
            val[k] = fmaf(w, fmaf(-w, u, val[cw.x]), u);
        }
        __syncthreads();
    }

    // epilogue: scattered b32 LDS reads, coalesced float4 stores
    float* ob = out + ((size_t)(b * CC + c)) * VV;
    #pragma unroll
    for (int t = 0; t < 4; ++t) {
        int idx = tid + t * 256;
        int4 kk = ((const int4*)ivB)[idx];
        float4 r;
        r.x = val[kk.x] * inrS[kk.x];
        r.y = val[kk.y] * inrS[kk.y];
        r.z = val[kk.z] * inrS[kk.z];
        r.w = val[kk.w] * inrS[kk.w];
        ((float4*)ob)[idx] = r;
    }
}

extern "C" void kernel_launch(void* const* d_in, const int* in_sizes, int n_in,
                              void* d_out, int out_size, void* d_ws, size_t ws_size,
                              hipStream_t stream) {
    const float* feat          = (const float*)d_in[0];
    const float* embed         = (const float*)d_in[1];
    const int*   sorted_index  = (const int*)d_in[2];
    const int*   sorted_parent = (const int*)d_in[3];
    const int*   node_level    = (const int*)d_in[4];
    float* out = (float*)d_out;

    char* ws = (char*)d_ws;
    const size_t A = (size_t)BB * VV * 4;     // 64 KB
    float* wsort = (float*)(ws);              // 64 KB
    int*   giInv = (int*)  (ws + A);          // 64 KB
    int2*  pw    = (int2*) (ws + 2 * A);      // 128 KB
    float* inr   = (float*)(ws + 4 * A);      // 64 KB
    int*   offs  = (int*)  (ws + 5 * A);      // 256 B

    weight_kernel<<<BB * 64, 256, 0, stream>>>(
        embed, sorted_index, sorted_parent, wsort);

    sortnrm_kernel<<<BB, 256, 0, stream>>>(
        sorted_index, sorted_parent, node_level, wsort, giInv, pw, inr, offs);

    tree_kernel<<<BB * CC, 256, 0, stream>>>(
        feat, giInv, pw, inr, offs, out);
}

// Round 6
// 115.895 us; speedup vs baseline: 1.0204x; 1.0204x over previous
//
#include <hip/hip_runtime.h>

// Problem constants (match reference setup_inputs).
#define BB 4
#define CC 128
#define CE 64
#define VV 4096
#define NLEV 14   // MAX_LEVELS

// Workspace layout:
//   wsort [BB*VV] float : edge weight of node at SORTED position i
//   giInv [BB*VV] int   : levelpos of pixel v
//   cpl   [BB*VV] int2  : {cp (levelpos of parent), sorted idx i} at levelpos k
//   offs  [BB*16] int   : level start offsets

__device__ __forceinline__ void lds_fadd(float* p, float v) {
    unsafeAtomicAdd(p, v);   // ds_add_f32 on gfx950 LDS
}

// ---------------------------------------------------------------------------
// K1 (fused): blocks [0,BB)           : per-batch counting sort -> tables
//             blocks [BB, BB+BB*64)   : edge weights in SORTED order
//             (independent of each other -> run concurrently in one launch)
// ---------------------------------------------------------------------------
__global__ __launch_bounds__(256) void prep_kernel(
    const float* __restrict__ embed,
    const int* __restrict__ sorted_index,
    const int* __restrict__ sorted_parent,
    const int* __restrict__ node_level,
    float* __restrict__ wsort,
    int*   __restrict__ giInv,
    int2*  __restrict__ cpl,
    int*   __restrict__ offs)
{
    int tid = threadIdx.x;
    if (blockIdx.x < BB) {
        int b = blockIdx.x;
        __shared__ int si_s[VV];
        __shared__ int pos_s[VV];
        __shared__ int lo_s[VV];
        __shared__ int hist[NLEV + 1];
        __shared__ int cursor[NLEV];
        __shared__ int offSh[NLEV + 1];
        const int* lev = node_level    + b * VV;
        const int* si  = sorted_index  + b * VV;
        const int* par = sorted_parent + b * VV;

        if (tid < NLEV + 1) hist[tid] = 0;
        __syncthreads();
        for (int i = tid; i < VV; i += 256) {
            si_s[i] = si[i];
            int d = lev[i]; d = d < NLEV - 1 ? d : NLEV - 1;
            atomicAdd(&hist[d], 1);
        }
        __syncthreads();
        if (tid == 0) {
            int acc = 0;
            for (int d = 0; d < NLEV; ++d) { int h = hist[d]; offSh[d] = acc; cursor[d] = acc; acc += h; }
            offSh[NLEV] = acc;
        }
        __syncthreads();
        if (tid <= NLEV) offs[b * 16 + tid] = offSh[tid];
        for (int i = tid; i < VV; i += 256) {
            int d = lev[i]; d = d < NLEV - 1 ? d : NLEV - 1;
            int k = atomicAdd(&cursor[d], 1);
            pos_s[i] = k;
            lo_s[k]  = i;
            giInv[b * VV + si_s[i]] = k;
        }
        __syncthreads();
        for (int k = tid; k < VV; k += 256) {
            int i = lo_s[k];
            cpl[b * VV + k] = make_int2(pos_s[par[i]], i);
        }
    } else {
        // weight: block = 64 nodes; wave w covers ce chunk [16w, 16w+16).
        __shared__ float part[4][64];
        int bb   = blockIdx.x - BB;
        int b    = bb >> 6;
        int n0   = (bb & 63) << 6;
        int lane = tid & 63;
        int w    = tid >> 6;
        int i    = n0 + lane;
        int vi = sorted_index[b * VV + i];
        int p  = sorted_parent[b * VV + i];
        int vp = sorted_index[b * VV + p];
        const float* eb = embed + (size_t)b * CE * VV;
        float acc = 0.f;
        #pragma unroll
        for (int r = 0; r < 16; ++r) {
            int ce = w * 16 + r;
            float d = eb[ce * VV + vi] - eb[ce * VV + vp];
            acc = fmaf(d, d, acc);
        }
        part[w][lane] = acc;
        __syncthreads();
        if (w == 0) {
            float d2 = part[0][lane] + part[1][lane] + part[2][lane] + part[3][lane];
            wsort[b * VV + i] = __expf(-d2);
        }
    }
}

// ---------------------------------------------------------------------------
// K2: per-(b,c) tree filter, fused {val,nrm} float2 chain. 512 threads
//     (8 waves), 64 KB LDS -> 2 blocks/CU, 16 waves/CU. Most level phases
//     finish in ONE iteration. All global traffic coalesced; one-time pack
//     step converts cw[k].y from sorted-idx to w-bits (wsort is L1-resident).
// ---------------------------------------------------------------------------
__global__ __launch_bounds__(512) void tree_kernel(
    const float* __restrict__ feat,
    const float* __restrict__ wsort,
    const int*  __restrict__ giInv,
    const int2* __restrict__ cpl,
    const int*  __restrict__ offs,
    float* __restrict__ out)
{
    __shared__ float2 vv[VV];   // 32 KB {val, nrm} by levelpos
    __shared__ int2   cw[VV];   // 32 KB {cp, sorted-idx -> w bits}
    __shared__ int    offS[16];
    int b   = blockIdx.x >> 7;  // CC = 128
    int c   = blockIdx.x & (CC - 1);
    int tid = threadIdx.x;

    const int2*  cplB = cpl   + b * VV;
    const int*   ivB  = giInv + b * VV;
    const float* wsB  = wsort + b * VV;
    const float* f    = feat + ((size_t)(b * CC + c)) * VV;

    if (tid < 16) offS[tid] = offs[b * 16 + tid];

    // stage {cp, i} pairs: coalesced int4 -> b128 LDS
    #pragma unroll
    for (int t = 0; t < 4; ++t) {
        int idx = tid + t * 512;
        ((int4*)cw)[idx] = ((const int4*)cplB)[idx];
    }

    // init: coalesced float4/int4 reads, scattered b64 LDS writes; keep kk
    int4 kkR[2];
    #pragma unroll
    for (int t = 0; t < 2; ++t) {
        int idx = tid + t * 512;
        float4 fv = ((const float4*)f)[idx];
        int4   kk = ((const int4*)ivB)[idx];
        kkR[t] = kk;
        vv[kk.x] = make_float2(fv.x, 1.f);
        vv[kk.y] = make_float2(fv.y, 1.f);
        vv[kk.z] = make_float2(fv.z, 1.f);
        vv[kk.w] = make_float2(fv.w, 1.f);
    }
    __syncthreads();

    // pack: cw[k].y = w bits (gather from 16 KB/batch wsort, cache-resident)
    #pragma unroll
    for (int t = 0; t < 8; ++t) {
        int k = tid + t * 512;
        cw[k].y = __float_as_int(wsB[cw[k].y]);
    }
    __syncthreads();

    // upward: parents of level d are exactly level d-1 -> phase-safe atomics
    for (int d = NLEV - 1; d >= 1; --d) {
        int s = offS[d], e = offS[d + 1];
        if (s == e) continue;                 // offS uniform -> safe skip
        for (int k = s + tid; k < e; k += 512) {
            int2 x = cw[k];
            float w = __int_as_float(x.y);
            float2 u = vv[k];
            lds_fadd(&vv[x.x].x, w * u.x);
            lds_fadd(&vv[x.x].y, w * u.y);
        }
        __syncthreads();
    }

    // downward: in place; parent (level d-1) final before level d reads it
    for (int d = 1; d <= NLEV - 1; ++d) {
        int s = offS[d], e = offS[d + 1];
        if (s == e) continue;
        for (int k = s + tid; k < e; k += 512) {
            int2 x = cw[k];
            float w = __int_as_float(x.y);
            float2 u  = vv[k];
            float2 pa = vv[x.x];
            vv[k] = make_float2(fmaf(w, fmaf(-w, u.x, pa.x), u.x),
                                fmaf(w, fmaf(-w, u.y, pa.y), u.y));
        }
        __syncthreads();
    }

    // epilogue: scattered b64 LDS reads, coalesced float4 stores
    float* ob = out + ((size_t)(b * CC + c)) * VV;
    #pragma unroll
    for (int t = 0; t < 2; ++t) {
        int idx = tid + t * 512;
        int4 kk = kkR[t];
        float2 u0 = vv[kk.x];
        float2 u1 = vv[kk.y];
        float2 u2 = vv[kk.z];
        float2 u3 = vv[kk.w];
        float4 r;
        r.x = __fdividef(u0.x, u0.y);
        r.y = __fdividef(u1.x, u1.y);
        r.z = __fdividef(u2.x, u2.y);
        r.w = __fdividef(u3.x, u3.y);
        ((float4*)ob)[idx] = r;
    }
}

extern "C" void kernel_launch(void* const* d_in, const int* in_sizes, int n_in,
                              void* d_out, int out_size, void* d_ws, size_t ws_size,
                              hipStream_t stream) {
    const float* feat          = (const float*)d_in[0];
    const float* embed         = (const float*)d_in[1];
    const int*   sorted_index  = (const int*)d_in[2];
    const int*   sorted_parent = (const int*)d_in[3];
    const int*   node_level    = (const int*)d_in[4];
    float* out = (float*)d_out;

    char* ws = (char*)d_ws;
    const size_t A = (size_t)BB * VV * 4;     // 64 KB
    float* wsort = (float*)(ws);              // 64 KB
    int*   giInv = (int*)  (ws + A);          // 64 KB
    int2*  cpl   = (int2*) (ws + 2 * A);      // 128 KB
    int*   offs  = (int*)  (ws + 4 * A);      // 256 B

    prep_kernel<<<BB + BB * 64, 256, 0, stream>>>(
        embed, sorted_index, sorted_parent, node_level, wsort, giInv, cpl, offs);

    tree_kernel<<<BB * CC, 512, 0, stream>>>(
        feat, wsort, giInv, cpl, offs, out);
}